// Round 13
// baseline (430.831 us; speedup 1.0000x reference)
//
#include <hip/hip_runtime.h>
#include <cstdint>
#include <math.h>

#define NB 128  // batch size

// ---------------------------------------------------------------------------
// Weight packing + integer bn thresholds.
// Layers 2-6: wp[ocg][pass][tap][lane][4]  (pass = group of 4 channel-words)
//   -> a wave's per-pass weights are 9 x dwordx4 per lane, tap offsets
//      t*1024B (mostly imm), perfectly coalesced 1024B per instruction.
// Layer 7:    wp[o][tap][cw] (unchanged).
// Layer 1:    wsf[oc*27 + t] = (w1 >= 0) ? +1.0f : -1.0f.
// thr[j] (j = global oc over layers 2..6): min integer d with
//   fl64(d*s + t) >= 0 -> bn sign decision == (dot >= thr), bit-identical
//   to the f64 reference.
// ---------------------------------------------------------------------------
__global__ void pack_all_kernel(
    const float* __restrict__ w1,
    const float* __restrict__ w2, const float* __restrict__ w3,
    const float* __restrict__ w4, const float* __restrict__ w5,
    const float* __restrict__ w6, const float* __restrict__ w7,
    const float* __restrict__ s2, const float* __restrict__ t2,
    const float* __restrict__ s3, const float* __restrict__ t3,
    const float* __restrict__ s4, const float* __restrict__ t4,
    const float* __restrict__ s5, const float* __restrict__ t5,
    const float* __restrict__ s6, const float* __restrict__ t6,
    float* __restrict__ wsf,
    uint32_t* __restrict__ wp2, uint32_t* __restrict__ wp3,
    uint32_t* __restrict__ wp4, uint32_t* __restrict__ wp5,
    uint32_t* __restrict__ wp6, uint32_t* __restrict__ wp7,
    int* __restrict__ thr) {
  int i = blockIdx.x * 256 + threadIdx.x;
  if (i >= 150528) return;              // 588 * 256 exact
  if (i >= 147072) {                    // conv1 signed float weights
    int j = i - 147072;                 // 0..3455 ; w1 is [128][27] contiguous
    wsf[j] = (w1[j] >= 0.0f) ? 1.0f : -1.0f;
    return;
  }
  if (i >= 145408) {  // integer thresholds for layers 2..6
    int j = i - 145408;  // 0..1663
    const float *bsp, *btp; int idx;
    if (j < 128)       { bsp = s2; btp = t2; idx = j; }
    else if (j < 384)  { bsp = s3; btp = t3; idx = j - 128; }
    else if (j < 640)  { bsp = s4; btp = t4; idx = j - 384; }
    else if (j < 1152) { bsp = s5; btp = t5; idx = j - 640; }
    else               { bsp = s6; btp = t6; idx = j - 1152; }
    const double s = (double)bsp[idx], t = (double)btp[idx];
    int d0 = (int)floor(-t / s);
    int th = d0 + 4;
    for (int d = d0 - 3; d <= d0 + 4; ++d)
      if ((double)d * s + t >= 0.0) { th = d; break; }
    thr[j] = th;
    return;
  }
  const float* w; uint32_t* wp; int C, KHW; bool nl = true;
  if (i < 4608)        { w = w2; wp = wp2; C = 128; KHW = 9; }
  else if (i < 13824)  { i -= 4608;   w = w3; wp = wp3; C = 128; KHW = 9; }
  else if (i < 32256)  { i -= 13824;  w = w4; wp = wp4; C = 256; KHW = 9; }
  else if (i < 69120)  { i -= 32256;  w = w5; wp = wp5; C = 256; KHW = 9; }
  else if (i < 142848) { i -= 69120;  w = w6; wp = wp6; C = 512; KHW = 9; }
  else                 { i -= 142848; w = w7; wp = wp7; C = 512; KHW = 16; nl = false; }
  int Cw = C >> 5;
  int cw = i % Cw;
  int rest = i / Cw;
  int t = rest % KHW;
  int o = rest / KHW;
  uint32_t word = 0;
  for (int b = 0; b < 32; ++b)
    word |= ((w[(o * C + cw * 32 + b) * KHW + t] >= 0.0f) ? 1u : 0u) << b;
  if (nl) {
    // [ocg][pass][tap][lane][4]: dwordx4-loadable, coalesced, imm offsets
    const int ocg = o >> 6, lane = o & 63, pass = cw >> 2, cwi = cw & 3;
    wp[(((ocg * (Cw >> 2) + pass) * 9 + t) * 64 + lane) * 4 + cwi] = word;
  } else {
    wp[(o * KHW + t) * Cw + cw] = word;
  }
}

// Guaranteed accumulating popcount: acc = popc(x) + acc (one VALU instr).
__device__ __forceinline__ void popc_acc(int& acc, uint32_t x) {
  asm("v_bcnt_u32_b32 %0, %1, %0" : "+v"(acc) : "v"(x));
}

// ---------------------------------------------------------------------------
// Conv1 — pixel-per-lane. Each thread owns one pixel; 27-tap fp32 window in
// VGPRs. Weights are PRE-SIGNED floats (+-1.0f) at wave-uniform addresses ->
// s_load -> SGPR; inner loop is exactly one v_fmac_f32 (SGPR weight operand)
// per MAC. 32-oc groups (blockIdx.y=0..3) -> 2048 blocks = 8/CU.
// f32 fmac + sound-threshold (1e-3*s) f64 fixup -> f64-exact sign decisions.
// ---------------------------------------------------------------------------
__global__ __launch_bounds__(256, 2) void conv1_kernel(
    const float* __restrict__ x, const float* __restrict__ wsf,
    const float* __restrict__ bs, const float* __restrict__ bt,
    uint32_t* __restrict__ out) {
  const int tid = blockIdx.x * 256 + threadIdx.x;  // pixel id (exact grid)
  const int og = blockIdx.y;                       // 32-oc group (0..3)
  const int px = tid & 31, py = (tid >> 5) & 31, n = tid >> 10;

  float xv[27];
#pragma unroll
  for (int ic = 0; ic < 3; ++ic)
#pragma unroll
    for (int kh = 0; kh < 3; ++kh) {
      const int yy = py + kh - 1;
      const int yc = min(max(yy, 0), 31);
      const float* row = x + ((n * 3 + ic) * 32 + yc) * 32;
#pragma unroll
      for (int kw = 0; kw < 3; ++kw) {
        const int xx = px + kw - 1;
        const int xc = min(max(xx, 0), 31);
        const float v = row[xc];
        const bool ok = ((unsigned)yy < 32u) && ((unsigned)xx < 32u);
        xv[ic * 9 + kh * 3 + kw] = ok ? v : 0.0f;
      }
    }

  uint32_t wout = 0;
  const float* wog = wsf + og * 32 * 27;  // uniform base
#pragma unroll
  for (int o4 = 0; o4 < 8; ++o4) {
    float a0 = 0.f, a1 = 0.f, a2 = 0.f, a3 = 0.f;
#pragma unroll
    for (int t = 0; t < 27; ++t) {  // 4 independent fmac chains, SGPR weights
      a0 = fmaf(xv[t], wog[(o4 * 4 + 0) * 27 + t], a0);
      a1 = fmaf(xv[t], wog[(o4 * 4 + 1) * 27 + t], a1);
      a2 = fmaf(xv[t], wog[(o4 * 4 + 2) * 27 + t], a2);
      a3 = fmaf(xv[t], wog[(o4 * 4 + 3) * 27 + t], a3);
    }
    float aa[4] = {a0, a1, a2, a3};
#pragma unroll
    for (int j = 0; j < 4; ++j) {
      const int ob = o4 * 4 + j;
      const int oc = og * 32 + ob;
      const float s = bs[oc], t0 = bt[oc];          // uniform scalars
      const float v = fmaf(aa[j], s, t0);
      bool pos = v >= 0.0f;
      if (fabsf(v) < 1e-3f * s) {                   // rare exact path
        double ad = 0.0;
        for (int t = 0; t < 27; ++t)
          ad += (double)wog[ob * 27 + t] * (double)xv[t];
        pos = (ad * (double)s + (double)t0) >= 0.0;
      }
      wout |= (pos ? 1u : 0u) << ob;
    }
  }
  out[tid * 4 + og] = wout;
}

// ---------------------------------------------------------------------------
// Binary conv 3x3 pad=1 — oc-in-lane, weight-stationary, LDS-staged act,
// INTEGER-threshold epilogue. R11 base: R=2, PC=4, CWP=4, WPB=4,
// launch_bounds(256,5), unroll-1 pass loop, popc_acc, dwordx4 weights,
// block-staged act tile. OCL reverted (R12: no instr savings, VGPR blowup).
//   R13 change: 2-row SOFTWARE PIPELINE on the act reads. bufA/bufB
//   (parity-selected at compile time after unroll) — row i+1's
//   ds_read_b128s are issued BEFORE row i's MAC block, so the ~120cy LDS
//   latency hides under the 96-288cy of row-i compute. Previously each
//   pass was 4-6 sequential load->compute chains = the 28-38% issue-idle
//   that six data-path levers failed to dent.
// Inner op: v_xor + accumulating v_bcnt via popc_acc (2 instr / 32 MACs).
// Sign bit: acc <= (32*nv - thr) >> 1  (thr precomputed, f64-exact).
// POOL: OR of the 2x2 ballots.
// ---------------------------------------------------------------------------
template <int CW, int CWP, int H, int W, int PC, int R, bool POOL, int WPB>
__global__ __launch_bounds__(64 * WPB, 5) void bconv_kernel(
    const uint32_t* __restrict__ act, const uint32_t* __restrict__ wpk,
    const int* __restrict__ thrp,
    uint32_t* __restrict__ out, int OCW) {
  static_assert(CW % CWP == 0 && CWP == 4, "");
  constexpr int CPR = W / PC;                       // column groups per row
  constexpr int SPANRG = (CPR >= WPB) ? 1 : (WPB / CPR);  // row-groups/block
  constexpr int S = SPANRG * R + 2;                 // staged rows (with halo)
  constexpr int RW = W * CW;                        // words per act row
  __shared__ uint32_t alds[S * RW];

  const int lane = threadIdx.x & 63;
  const int ocg = blockIdx.y;
  // block-uniform image / row-group base (gb aligned to WPB)
  const int gb = blockIdx.x * WPB;
  const int nB  = gb / (CPR * (H / R));
  const int rg0 = (gb / CPR) % (H / R);
  const int ymin = rg0 * R - 1;

  // cooperative staging: S rows x full width x all CW, coalesced dwordx4
  {
    const uint32_t* actn = act + (size_t)nB * H * RW;
    for (int idx = threadIdx.x; idx < S * RW / 4; idx += 64 * WPB) {
      const int s = idx / (RW / 4);
      const int c4 = idx - s * (RW / 4);
      const int y = ymin + s;
      if ((unsigned)y < (unsigned)H)
        *(uint4*)&alds[s * RW + c4 * 4] =
            *(const uint4*)(actn + (size_t)y * RW + c4 * 4);
    }
  }
  __syncthreads();

  // wave-uniform pixel-group id, provably scalar via readfirstlane
  const int wid = __builtin_amdgcn_readfirstlane((int)(threadIdx.x >> 6));
  const int g = gb + wid;
  const int cg = g % CPR;
  const int rg = (g / CPR) % (H / R);
  const int y0 = rg * R, x0 = cg * PC;

  const int thr = thrp[ocg * 64 + lane];

  int acc[R * PC];
#pragma unroll
  for (int p = 0; p < R * PC; ++p) acc[p] = 0;

#pragma unroll 1
  for (int pass = 0; pass < CW / CWP; ++pass) {
    uint32_t wreg[9 * CWP];
    {
      const uint32_t* wbase =
          wpk + (((ocg * (CW / CWP) + pass) * 9) * 64 + lane) * 4;
#pragma unroll
      for (int t = 0; t < 9; ++t)
        *(uint4*)&wreg[t * 4] = *(const uint4*)(wbase + t * 256);
    }

    uint32_t bufA[(PC + 2) * CWP], bufB[(PC + 2) * CWP];
    auto LOADROW = [&](int yy, uint32_t* bf) {
      const uint32_t* lr = alds + (yy - ymin) * RW + x0 * CW + pass * CWP;
#pragma unroll
      for (int cc = -1; cc <= PC; ++cc) {
        const int x = x0 + cc;
        if (x < 0 || x >= W) continue;            // scalar branch
        *(uint4*)&bf[(cc + 1) * CWP] = *(const uint4*)(lr + cc * CW);
      }
    };

    // pipeline prologue: first valid row into its parity buffer
    if (y0 > 0) LOADROW(y0 - 1, bufA);            // ry=-1 -> parity 0
    else        LOADROW(y0, bufB);                // ry= 0 -> parity 1

#pragma unroll
    for (int ry = -1; ry <= R; ++ry) {
      const int y = y0 + ry;
      if (y < 0 || y >= H) continue;              // scalar branch
      uint32_t* cur = (((ry + 1) & 1) ? bufB : bufA);   // compile-time
      uint32_t* nxt = (((ry + 2) & 1) ? bufB : bufA);   // compile-time
      if (ry < R && y + 1 < H) LOADROW(y + 1, nxt);     // prefetch next row
#pragma unroll
      for (int cc = -1; cc <= PC; ++cc) {         // compute from registers
        const int x = x0 + cc;
        if (x < 0 || x >= W) continue;            // scalar branch
#pragma unroll
        for (int r = 0; r < R; ++r) {
          const int kh = ry - r + 1;              // compile-time after unroll
          if (kh < 0 || kh > 2) continue;
#pragma unroll
          for (int kw = 0; kw < 3; ++kw) {
            const int pxo = cc - kw + 1;          // compile-time
            if (pxo < 0 || pxo >= PC) continue;
#pragma unroll
            for (int cw = 0; cw < CWP; ++cw)
              popc_acc(acc[r * PC + pxo],
                       cur[(cc + 1) * CWP + cw] ^ wreg[(kh * 3 + kw) * CWP + cw]);
          }
        }
      }
    }
  }

  if (!POOL) {
    uint64_t bal[R * PC];
#pragma unroll
    for (int r = 0; r < R; ++r)
#pragma unroll
      for (int pxo = 0; pxo < PC; ++pxo) {
        const int y = y0 + r, x = x0 + pxo;
        const int nv32 =
            32 * CW * (3 - (y == 0) - (y == H - 1)) * (3 - (x == 0) - (x == W - 1));
        bal[r * PC + pxo] = __ballot(acc[r * PC + pxo] <= ((nv32 - thr) >> 1));
      }
    if (lane == 0) {
#pragma unroll
      for (int r = 0; r < R; ++r)
#pragma unroll
        for (int pxo = 0; pxo < PC; ++pxo)
          *(uint64_t*)(out + ((nB * H + (y0 + r)) * W + (x0 + pxo)) * OCW + ocg * 2) =
              bal[r * PC + pxo];
    }
  } else {
    static_assert(!POOL || R == 2, "pool needs row pairs");
    uint64_t pooled[PC / 2];
#pragma unroll
    for (int c2 = 0; c2 < PC / 2; ++c2) pooled[c2] = 0;
#pragma unroll
    for (int r = 0; r < R; ++r)
#pragma unroll
      for (int pxo = 0; pxo < PC; ++pxo) {
        const int y = y0 + r, x = x0 + pxo;
        const int nv32 =
            32 * CW * (3 - (y == 0) - (y == H - 1)) * (3 - (x == 0) - (x == W - 1));
        pooled[pxo >> 1] |= __ballot(acc[r * PC + pxo] <= ((nv32 - thr) >> 1));
      }
    if (lane == 0) {
#pragma unroll
      for (int c2 = 0; c2 < PC / 2; ++c2) {
        const int yo = y0 >> 1, xo = (x0 >> 1) + c2;
        *(uint64_t*)(out + ((nB * (H / 2) + yo) * (W / 2) + xo) * OCW + ocg * 2) =
            pooled[c2];
      }
    }
  }
}

// ---------------------------------------------------------------------------
// Conv7 (4x4 VALID, K=512*16=8192 = 256 words) + bn7 + log_softmax (double)
// One block (1 wave) per image.
// ---------------------------------------------------------------------------
__global__ __launch_bounds__(64) void conv7_kernel(
    const uint32_t* __restrict__ act, const uint32_t* __restrict__ wp,
    const float* __restrict__ bs, const float* __restrict__ bt,
    float* __restrict__ out) {
  int n = blockIdx.x;
  int lane = threadIdx.x;
  const uint32_t* a = act + n * 256;
  __shared__ double logits[10];
  for (int o = 0; o < 10; ++o) {
    int acc = 0;
    for (int w = lane; w < 256; w += 64) acc += __popc(a[w] ^ wp[o * 256 + w]);
    for (int off = 32; off > 0; off >>= 1) acc += __shfl_down(acc, off, 64);
    if (lane == 0) {
      double dotd = (double)(8192 - 2 * acc);
      logits[o] = dotd * (double)bs[o] + (double)bt[o];
    }
  }
  __syncthreads();
  if (lane == 0) {
    double m = logits[0];
    for (int o = 1; o < 10; ++o) m = fmax(m, logits[o]);
    double s = 0.0;
    for (int o = 0; o < 10; ++o) s += exp(logits[o] - m);
    double lse = log(s);
    for (int o = 0; o < 10; ++o) out[n * 10 + o] = (float)(logits[o] - m - lse);
  }
}

// ---------------------------------------------------------------------------
extern "C" void kernel_launch(void* const* d_in, const int* in_sizes, int n_in,
                              void* d_out, int out_size, void* d_ws, size_t ws_size,
                              hipStream_t stream) {
  const float* x  = (const float*)d_in[0];
  const float* w1 = (const float*)d_in[1];
  const float* w2 = (const float*)d_in[2];
  const float* w3 = (const float*)d_in[3];
  const float* w4 = (const float*)d_in[4];
  const float* w5 = (const float*)d_in[5];
  const float* w6 = (const float*)d_in[6];
  const float* w7 = (const float*)d_in[7];
  const float* s1 = (const float*)d_in[8];  const float* t1 = (const float*)d_in[9];
  const float* s2 = (const float*)d_in[10]; const float* t2 = (const float*)d_in[11];
  const float* s3 = (const float*)d_in[12]; const float* t3 = (const float*)d_in[13];
  const float* s4 = (const float*)d_in[14]; const float* t4 = (const float*)d_in[15];
  const float* s5 = (const float*)d_in[16]; const float* t5 = (const float*)d_in[17];
  const float* s6 = (const float*)d_in[18]; const float* t6 = (const float*)d_in[19];
  const float* s7 = (const float*)d_in[20]; const float* t7 = (const float*)d_in[21];
  float* out = (float*)d_out;

  uint32_t* ws = (uint32_t*)d_ws;
  uint32_t* A   = ws;                 // 524288 words (2 MB) ping
  uint32_t* B   = ws + 524288;        // 524288 words pong
  uint32_t* wp2 = ws + 1048576;       // 2*1*9*256  = 4608
  uint32_t* wp3 = wp2 + 4608;         // 4*1*9*256  = 9216
  uint32_t* wp4 = wp3 + 9216;         // 4*2*9*256  = 18432
  uint32_t* wp5 = wp4 + 18432;        // 8*2*9*256  = 36864
  uint32_t* wp6 = wp5 + 36864;        // 8*4*9*256  = 73728
  uint32_t* wp7 = wp6 + 73728;        // 10*16*16   = 2560
  float* wsf    = (float*)(wp7 + 2560);  // 128*27 = 3456 signed float conv1 wts
  int* thr      = (int*)(wsf + 3456);    // 1664 ints: L2@0 L3@128 L4@384 L5@640 L6@1152

  // pack all weights + thresholds in one dispatch (ws re-poisoned -> repack)
  pack_all_kernel<<<dim3(588), dim3(256), 0, stream>>>(
      w1, w2, w3, w4, w5, w6, w7,
      s2, t2, s3, t3, s4, t4, s5, t5, s6, t6,
      wsf, wp2, wp3, wp4, wp5, wp6, wp7, thr);

  // L1: conv1 pixel-per-lane (SGPR signed-float weights) -> A [128,32,32,4]
  conv1_kernel<<<dim3(512, 4), dim3(256), 0, stream>>>(x, wsf, s1, t1, A);

  // L2: bconv+pool (CW=4, 32x32) A->B [128,16,16,4]
  bconv_kernel<4, 4, 32, 32, 4, 2, true, 4>
      <<<dim3(4096, 2), dim3(256), 0, stream>>>(A, wp2, thr + 0, B, 4);

  // L3: bconv (CW=4, 16x16, OC=256) B->A [128,16,16,8]
  bconv_kernel<4, 4, 16, 16, 4, 2, false, 4>
      <<<dim3(1024, 4), dim3(256), 0, stream>>>(B, wp3, thr + 128, A, 8);

  // L4: bconv+pool (CW=8 in 2 passes of 4) A->B [128,8,8,8]
  bconv_kernel<8, 4, 16, 16, 4, 2, true, 4>
      <<<dim3(1024, 4), dim3(256), 0, stream>>>(A, wp4, thr + 384, B, 8);

  // L5: bconv (CW=8 in 2 passes of 4, 8x8, OC=512) B->A [128,8,8,16]
  bconv_kernel<8, 4, 8, 8, 4, 2, false, 4>
      <<<dim3(256, 8), dim3(256), 0, stream>>>(B, wp5, thr + 640, A, 16);

  // L6: bconv+pool (CW=16 in 4 passes of 4) A->B [128,4,4,16]
  bconv_kernel<16, 4, 8, 8, 4, 2, true, 4>
      <<<dim3(256, 8), dim3(256), 0, stream>>>(A, wp6, thr + 1152, B, 16);

  // L7: conv7 + bn7 + log_softmax -> out [128,10]
  conv7_kernel<<<dim3(128), dim3(64), 0, stream>>>(B, wp7, s7, t7, out);
}

// Round 14
// 286.336 us; speedup vs baseline: 1.5046x; 1.5046x over previous
//
#include <hip/hip_runtime.h>
#include <cstdint>
#include <math.h>

#define NB 128  // batch size

// ---------------------------------------------------------------------------
// Weight packing + integer bn thresholds.
// Layers 2-6: wp[ocg][tap][cw][oc64] (oc64 = lane).
// Layer 7:    wp[o][tap][cw].
// Layer 1:    wsf[oc*27 + t] = (w1 >= 0) ? +1.0f : -1.0f  (signed float wts;
//             loaded wave-uniformly in conv1 -> SGPRs -> 1 v_fmac per MAC).
// thr[j] (j = global oc over layers 2..6): min integer d with
//   fl64(d*s + t) >= 0  (d*s exact since d<2^14, s has 24-bit mantissa;
//   fl64 monotone in d) -> bn sign decision == (dot >= thr), bit-identical
//   to the f64 reference.
// ---------------------------------------------------------------------------
__global__ void pack_all_kernel(
    const float* __restrict__ w1,
    const float* __restrict__ w2, const float* __restrict__ w3,
    const float* __restrict__ w4, const float* __restrict__ w5,
    const float* __restrict__ w6, const float* __restrict__ w7,
    const float* __restrict__ s2, const float* __restrict__ t2,
    const float* __restrict__ s3, const float* __restrict__ t3,
    const float* __restrict__ s4, const float* __restrict__ t4,
    const float* __restrict__ s5, const float* __restrict__ t5,
    const float* __restrict__ s6, const float* __restrict__ t6,
    float* __restrict__ wsf,
    uint32_t* __restrict__ wp2, uint32_t* __restrict__ wp3,
    uint32_t* __restrict__ wp4, uint32_t* __restrict__ wp5,
    uint32_t* __restrict__ wp6, uint32_t* __restrict__ wp7,
    int* __restrict__ thr) {
  int i = blockIdx.x * 256 + threadIdx.x;
  if (i >= 150528) return;              // 588 * 256 exact
  if (i >= 147072) {                    // conv1 signed float weights
    int j = i - 147072;                 // 0..3455 ; w1 is [128][27] contiguous
    wsf[j] = (w1[j] >= 0.0f) ? 1.0f : -1.0f;
    return;
  }
  if (i >= 145408) {  // integer thresholds for layers 2..6
    int j = i - 145408;  // 0..1663
    const float *bsp, *btp; int idx;
    if (j < 128)       { bsp = s2; btp = t2; idx = j; }
    else if (j < 384)  { bsp = s3; btp = t3; idx = j - 128; }
    else if (j < 640)  { bsp = s4; btp = t4; idx = j - 384; }
    else if (j < 1152) { bsp = s5; btp = t5; idx = j - 640; }
    else               { bsp = s6; btp = t6; idx = j - 1152; }
    const double s = (double)bsp[idx], t = (double)btp[idx];
    int d0 = (int)floor(-t / s);
    int th = d0 + 4;
    for (int d = d0 - 3; d <= d0 + 4; ++d)
      if ((double)d * s + t >= 0.0) { th = d; break; }
    thr[j] = th;
    return;
  }
  const float* w; uint32_t* wp; int C, KHW; bool nl = true;
  if (i < 4608)        { w = w2; wp = wp2; C = 128; KHW = 9; }
  else if (i < 13824)  { i -= 4608;   w = w3; wp = wp3; C = 128; KHW = 9; }
  else if (i < 32256)  { i -= 13824;  w = w4; wp = wp4; C = 256; KHW = 9; }
  else if (i < 69120)  { i -= 32256;  w = w5; wp = wp5; C = 256; KHW = 9; }
  else if (i < 142848) { i -= 69120;  w = w6; wp = wp6; C = 512; KHW = 9; }
  else                 { i -= 142848; w = w7; wp = wp7; C = 512; KHW = 16; nl = false; }
  int Cw = C >> 5;
  int cw = i % Cw;
  int rest = i / Cw;
  int t = rest % KHW;
  int o = rest / KHW;
  uint32_t word = 0;
  for (int b = 0; b < 32; ++b)
    word |= ((w[(o * C + cw * 32 + b) * KHW + t] >= 0.0f) ? 1u : 0u) << b;
  if (nl) wp[(((o >> 6) * KHW + t) * Cw + cw) * 64 + (o & 63)] = word;
  else    wp[(o * KHW + t) * Cw + cw] = word;
}

// A zero the compiler must treat as divergent (bconv act base addr -> VMEM).
__device__ __forceinline__ int v_zero() {
  return __builtin_amdgcn_ds_bpermute(0, 0);
}

// Guaranteed accumulating popcount: acc = popc(x) + acc (one VALU instr).
// hipcc was emitting the 3-instr form (v_bcnt dst,src,0 + v_add); the ISA's
// v_bcnt_u32_b32 has an accumulate operand -> force the 2-instr xor+bcnt pair.
__device__ __forceinline__ void popc_acc(int& acc, uint32_t x) {
  asm("v_bcnt_u32_b32 %0, %1, %0" : "+v"(acc) : "v"(x));
}

// ---------------------------------------------------------------------------
// Conv1 — pixel-per-lane. Each thread owns one pixel; 27-tap fp32 window in
// VGPRs. Weights are PRE-SIGNED floats (+-1.0f) at wave-uniform addresses ->
// s_load -> SGPR; inner loop is exactly one v_fmac_f32 (SGPR weight operand)
// per MAC. 32-oc groups (blockIdx.y=0..3) -> 2048 blocks = 8/CU.
// f32 fmac + sound-threshold (1e-3*s) f64 fixup -> f64-exact sign decisions.
// ---------------------------------------------------------------------------
__global__ __launch_bounds__(256, 2) void conv1_kernel(
    const float* __restrict__ x, const float* __restrict__ wsf,
    const float* __restrict__ bs, const float* __restrict__ bt,
    uint32_t* __restrict__ out) {
  const int tid = blockIdx.x * 256 + threadIdx.x;  // pixel id (exact grid)
  const int og = blockIdx.y;                       // 32-oc group (0..3)
  const int px = tid & 31, py = (tid >> 5) & 31, n = tid >> 10;

  float xv[27];
#pragma unroll
  for (int ic = 0; ic < 3; ++ic)
#pragma unroll
    for (int kh = 0; kh < 3; ++kh) {
      const int yy = py + kh - 1;
      const int yc = min(max(yy, 0), 31);
      const float* row = x + ((n * 3 + ic) * 32 + yc) * 32;
#pragma unroll
      for (int kw = 0; kw < 3; ++kw) {
        const int xx = px + kw - 1;
        const int xc = min(max(xx, 0), 31);
        const float v = row[xc];
        const bool ok = ((unsigned)yy < 32u) && ((unsigned)xx < 32u);
        xv[ic * 9 + kh * 3 + kw] = ok ? v : 0.0f;
      }
    }

  uint32_t wout = 0;
  const float* wog = wsf + og * 32 * 27;  // uniform base
#pragma unroll
  for (int o4 = 0; o4 < 8; ++o4) {
    float a0 = 0.f, a1 = 0.f, a2 = 0.f, a3 = 0.f;
#pragma unroll
    for (int t = 0; t < 27; ++t) {  // 4 independent fmac chains, SGPR weights
      a0 = fmaf(xv[t], wog[(o4 * 4 + 0) * 27 + t], a0);
      a1 = fmaf(xv[t], wog[(o4 * 4 + 1) * 27 + t], a1);
      a2 = fmaf(xv[t], wog[(o4 * 4 + 2) * 27 + t], a2);
      a3 = fmaf(xv[t], wog[(o4 * 4 + 3) * 27 + t], a3);
    }
    float aa[4] = {a0, a1, a2, a3};
#pragma unroll
    for (int j = 0; j < 4; ++j) {
      const int ob = o4 * 4 + j;
      const int oc = og * 32 + ob;
      const float s = bs[oc], t0 = bt[oc];          // uniform scalars
      const float v = fmaf(aa[j], s, t0);
      bool pos = v >= 0.0f;
      if (fabsf(v) < 1e-3f * s) {                   // rare exact path
        double ad = 0.0;
        for (int t = 0; t < 27; ++t)
          ad += (double)wog[ob * 27 + t] * (double)xv[t];
        pos = (ad * (double)s + (double)t0) >= 0.0;
      }
      wout |= (pos ? 1u : 0u) << ob;
    }
  }
  out[tid * 4 + og] = wout;
}

// ---------------------------------------------------------------------------
// Binary conv 3x3 pad=1 — oc-in-lane, weight-stationary, row-batched loads,
// INTEGER-threshold epilogue. R1's proven per-wave geometry (PC=4, CWP=4,
// uint4 act loads) untouched.
//   lane = oc in the wave's 64-oc group (blockIdx.y).
//   WPB=4 waves per block; g via readfirstlane -> scalar addressing.
//   __launch_bounds__(256, 5) + #pragma unroll 1 on the pass loop: ~102-reg
//   budget -> 5 waves/SIMD (R5, +5us over min-waves=4).
// Inner op: v_xor + accumulating v_bcnt via popc_acc (2 instr / 32 MACs,
// enforced by inline asm — hipcc was emitting the 3-instr non-accum form).
// Sign bit: acc <= (32*nv - thr) >> 1  (thr precomputed, f64-exact).
// POOL: OR of the 2x2 ballots.
// Session post-mortem (R8-R13): 7 further levers tested — launch-bounds 6
// (null), R=4 (VGPR 160 -> -8%), weight dwordx4 (null), LDS act staging
// (null), OCL oc-fold (VGPR 144 -> -8%), 2-row pipeline (spill -> -50%).
// This configuration is the measured optimum of the structure (287.7us).
// ---------------------------------------------------------------------------
template <int CW, int CWP, int H, int W, int PC, int R, bool POOL, int WPB>
__global__ __launch_bounds__(64 * WPB, 5) void bconv_kernel(
    const uint32_t* __restrict__ act, const uint32_t* __restrict__ wpk,
    const int* __restrict__ thrp,
    uint32_t* __restrict__ out, int OCW) {
  static_assert(CW % CWP == 0 && CWP % 4 == 0, "");
  const int lane = threadIdx.x & 63;
  const int ocg = blockIdx.y;
  const int zero = v_zero();
  const int cpr = W / PC;
  // wave-uniform pixel-group id, provably scalar via readfirstlane
  const int wid = __builtin_amdgcn_readfirstlane((int)(threadIdx.x >> 6));
  const int g = blockIdx.x * WPB + wid;
  const int cg = g % cpr;
  const int rg = (g / cpr) % (H / R);
  const int n  = g / (cpr * (H / R));
  const int y0 = rg * R, x0 = cg * PC;

  const int thr = thrp[ocg * 64 + lane];

  int acc[R * PC];
#pragma unroll
  for (int p = 0; p < R * PC; ++p) acc[p] = 0;

#pragma unroll 1
  for (int pass = 0; pass < CW / CWP; ++pass) {
    uint32_t wreg[9 * CWP];
#pragma unroll
    for (int t = 0; t < 9; ++t)
#pragma unroll
      for (int cw = 0; cw < CWP; ++cw)
        wreg[t * CWP + cw] = wpk[(((ocg * 9) + t) * CW + pass * CWP + cw) * 64 + lane];

#pragma unroll
    for (int ry = -1; ry <= R; ++ry) {
      const int y = y0 + ry;
      if (y < 0 || y >= H) continue;            // scalar branch
      const uint32_t* rowp = act + zero + (((size_t)n * H + y) * W + x0) * CW + pass * CWP;
      uint32_t buf[(PC + 2) * CWP];
#pragma unroll
      for (int cc = -1; cc <= PC; ++cc) {       // batched loads, imm offsets
        const int x = x0 + cc;
        if (x < 0 || x >= W) continue;          // scalar branch
#pragma unroll
        for (int q = 0; q < CWP / 4; ++q)
          *(uint4*)&buf[(cc + 1) * CWP + q * 4] =
              *(const uint4*)(rowp + cc * CW + q * 4);
      }
#pragma unroll
      for (int cc = -1; cc <= PC; ++cc) {       // compute from registers
        const int x = x0 + cc;
        if (x < 0 || x >= W) continue;          // scalar branch
#pragma unroll
        for (int r = 0; r < R; ++r) {
          const int kh = ry - r + 1;            // compile-time after unroll
          if (kh < 0 || kh > 2) continue;
#pragma unroll
          for (int kw = 0; kw < 3; ++kw) {
            const int pxo = cc - kw + 1;        // compile-time
            if (pxo < 0 || pxo >= PC) continue;
#pragma unroll
            for (int cw = 0; cw < CWP; ++cw)
              popc_acc(acc[r * PC + pxo],
                       buf[(cc + 1) * CWP + cw] ^ wreg[(kh * 3 + kw) * CWP + cw]);
          }
        }
      }
    }
  }

  if (!POOL) {
    uint64_t bal[R * PC];
#pragma unroll
    for (int r = 0; r < R; ++r)
#pragma unroll
      for (int pxo = 0; pxo < PC; ++pxo) {
        const int y = y0 + r, x = x0 + pxo;
        const int nv32 =
            32 * CW * (3 - (y == 0) - (y == H - 1)) * (3 - (x == 0) - (x == W - 1));
        bal[r * PC + pxo] = __ballot(acc[r * PC + pxo] <= ((nv32 - thr) >> 1));
      }
    if (lane == 0) {
#pragma unroll
      for (int r = 0; r < R; ++r)
#pragma unroll
        for (int pxo = 0; pxo < PC; ++pxo)
          *(uint64_t*)(out + ((n * H + (y0 + r)) * W + (x0 + pxo)) * OCW + ocg * 2) =
              bal[r * PC + pxo];
    }
  } else {
    static_assert(!POOL || R == 2, "pool needs row pairs");
    uint64_t pooled[PC / 2];
#pragma unroll
    for (int c2 = 0; c2 < PC / 2; ++c2) pooled[c2] = 0;
#pragma unroll
    for (int r = 0; r < R; ++r)
#pragma unroll
      for (int pxo = 0; pxo < PC; ++pxo) {
        const int y = y0 + r, x = x0 + pxo;
        const int nv32 =
            32 * CW * (3 - (y == 0) - (y == H - 1)) * (3 - (x == 0) - (x == W - 1));
        pooled[pxo >> 1] |= __ballot(acc[r * PC + pxo] <= ((nv32 - thr) >> 1));
      }
    if (lane == 0) {
#pragma unroll
      for (int c2 = 0; c2 < PC / 2; ++c2) {
        const int yo = y0 >> 1, xo = (x0 >> 1) + c2;
        *(uint64_t*)(out + ((n * (H / 2) + yo) * (W / 2) + xo) * OCW + ocg * 2) =
            pooled[c2];
      }
    }
  }
}

// ---------------------------------------------------------------------------
// Conv7 (4x4 VALID, K=512*16=8192 = 256 words) + bn7 + log_softmax (double)
// One block (1 wave) per image.
// ---------------------------------------------------------------------------
__global__ __launch_bounds__(64) void conv7_kernel(
    const uint32_t* __restrict__ act, const uint32_t* __restrict__ wp,
    const float* __restrict__ bs, const float* __restrict__ bt,
    float* __restrict__ out) {
  int n = blockIdx.x;
  int lane = threadIdx.x;
  const uint32_t* a = act + n * 256;
  __shared__ double logits[10];
  for (int o = 0; o < 10; ++o) {
    int acc = 0;
    for (int w = lane; w < 256; w += 64) acc += __popc(a[w] ^ wp[o * 256 + w]);
    for (int off = 32; off > 0; off >>= 1) acc += __shfl_down(acc, off, 64);
    if (lane == 0) {
      double dotd = (double)(8192 - 2 * acc);
      logits[o] = dotd * (double)bs[o] + (double)bt[o];
    }
  }
  __syncthreads();
  if (lane == 0) {
    double m = logits[0];
    for (int o = 1; o < 10; ++o) m = fmax(m, logits[o]);
    double s = 0.0;
    for (int o = 0; o < 10; ++o) s += exp(logits[o] - m);
    double lse = log(s);
    for (int o = 0; o < 10; ++o) out[n * 10 + o] = (float)(logits[o] - m - lse);
  }
}

// ---------------------------------------------------------------------------
extern "C" void kernel_launch(void* const* d_in, const int* in_sizes, int n_in,
                              void* d_out, int out_size, void* d_ws, size_t ws_size,
                              hipStream_t stream) {
  const float* x  = (const float*)d_in[0];
  const float* w1 = (const float*)d_in[1];
  const float* w2 = (const float*)d_in[2];
  const float* w3 = (const float*)d_in[3];
  const float* w4 = (const float*)d_in[4];
  const float* w5 = (const float*)d_in[5];
  const float* w6 = (const float*)d_in[6];
  const float* w7 = (const float*)d_in[7];
  const float* s1 = (const float*)d_in[8];  const float* t1 = (const float*)d_in[9];
  const float* s2 = (const float*)d_in[10]; const float* t2 = (const float*)d_in[11];
  const float* s3 = (const float*)d_in[12]; const float* t3 = (const float*)d_in[13];
  const float* s4 = (const float*)d_in[14]; const float* t4 = (const float*)d_in[15];
  const float* s5 = (const float*)d_in[16]; const float* t5 = (const float*)d_in[17];
  const float* s6 = (const float*)d_in[18]; const float* t6 = (const float*)d_in[19];
  const float* s7 = (const float*)d_in[20]; const float* t7 = (const float*)d_in[21];
  float* out = (float*)d_out;

  uint32_t* ws = (uint32_t*)d_ws;
  uint32_t* A   = ws;                 // 524288 words (2 MB) ping
  uint32_t* B   = ws + 524288;        // 524288 words pong
  uint32_t* wp2 = ws + 1048576;       // 2*9*4*64   = 4608
  uint32_t* wp3 = wp2 + 4608;         // 4*9*4*64   = 9216
  uint32_t* wp4 = wp3 + 9216;         // 4*9*8*64   = 18432
  uint32_t* wp5 = wp4 + 18432;        // 8*9*8*64   = 36864
  uint32_t* wp6 = wp5 + 36864;        // 8*9*16*64  = 73728
  uint32_t* wp7 = wp6 + 73728;        // 10*16*16   = 2560
  float* wsf    = (float*)(wp7 + 2560);  // 128*27 = 3456 signed float conv1 wts
  int* thr      = (int*)(wsf + 3456);    // 1664 ints: L2@0 L3@128 L4@384 L5@640 L6@1152

  // pack all weights + thresholds in one dispatch (ws re-poisoned -> repack)
  pack_all_kernel<<<dim3(588), dim3(256), 0, stream>>>(
      w1, w2, w3, w4, w5, w6, w7,
      s2, t2, s3, t3, s4, t4, s5, t5, s6, t6,
      wsf, wp2, wp3, wp4, wp5, wp6, wp7, thr);

  // L1: conv1 pixel-per-lane (SGPR signed-float weights) -> A [128,32,32,4]
  conv1_kernel<<<dim3(512, 4), dim3(256), 0, stream>>>(x, wsf, s1, t1, A);

  // L2: bconv+pool (CW=4, 32x32) A->B [128,16,16,4]
  // pixel-groups = 128*128 = 16384 -> 4096 blocks of 4 waves
  bconv_kernel<4, 4, 32, 32, 4, 2, true, 4>
      <<<dim3(4096, 2), dim3(256), 0, stream>>>(A, wp2, thr + 0, B, 4);

  // L3: bconv (CW=4, 16x16, OC=256) B->A [128,16,16,8]
  // pixel-groups = 128*32 = 4096 -> 1024 blocks
  bconv_kernel<4, 4, 16, 16, 4, 2, false, 4>
      <<<dim3(1024, 4), dim3(256), 0, stream>>>(B, wp3, thr + 128, A, 8);

  // L4: bconv+pool (CW=8 in 2 passes of 4) A->B [128,8,8,8]
  bconv_kernel<8, 4, 16, 16, 4, 2, true, 4>
      <<<dim3(1024, 4), dim3(256), 0, stream>>>(A, wp4, thr + 384, B, 8);

  // L5: bconv (CW=8 in 2 passes of 4, 8x8, OC=512) B->A [128,8,8,16]
  // pixel-groups = 128*8 = 1024 -> 256 blocks
  bconv_kernel<8, 4, 8, 8, 4, 2, false, 4>
      <<<dim3(256, 8), dim3(256), 0, stream>>>(B, wp5, thr + 640, A, 16);

  // L6: bconv+pool (CW=16 in 4 passes of 4) A->B [128,4,4,16]
  bconv_kernel<16, 4, 8, 8, 4, 2, true, 4>
      <<<dim3(256, 8), dim3(256), 0, stream>>>(A, wp6, thr + 1152, B, 16);

  // L7: conv7 + bn7 + log_softmax -> out [128,10]
  conv7_kernel<<<dim3(128), dim3(64), 0, stream>>>(B, wp7, s7, t7, out);
}